// Round 9
// baseline (119.543 us; speedup 1.0000x reference)
//
#include <hip/hip_runtime.h>
#include <hip/hip_bf16.h>

// pointconv: density MLP + weight-net + per-point [64x32]x[32x32] + [128x2048] GEMV + BN
// B=16 NP=1024 NS=32 CIN=64 CMID=32 COUT=128. Inputs f32, outputs f32 (bf16 MFMA inside).
// R7 lesson: F reads are 64-line/64-page divergent per wave-inst (p-stride = 4KB page).
// Fix: k_xpose relayouts F into bf16 tiles read page-densely by k_main.
// R8 bug (fixed): tile strides were 2x inflated (pw*4096/cblk*1024) -> tiles overlapped.
// Correct bijective tile layout: idx = pw*2048 + cblk*512 + sg*128 + l15*8 + j  (32768 u16/tile).

#define NPP 1024
#define NSS 32

typedef __attribute__((ext_vector_type(8))) short short8;
typedef __attribute__((ext_vector_type(4))) float f32x4;

__device__ __forceinline__ unsigned short f2bf(float x) {
  union { float f; unsigned u; } v; v.f = x;
  unsigned r = v.u + 0x7FFFu + ((v.u >> 16) & 1u);   // RNE
  return (unsigned short)(r >> 16);
}

__device__ __forceinline__ unsigned long long pack4bf(f32x4 v) {
  return (unsigned long long)f2bf(v[0])
       | ((unsigned long long)f2bf(v[1]) << 16)
       | ((unsigned long long)f2bf(v[2]) << 32)
       | ((unsigned long long)f2bf(v[3]) << 48);
}

// ---- k_prep: OWb[o][kflat] bf16 (kflat = cblk*512 + k*16 + c_off) + output-0 transpose ----
__global__ __launch_bounds__(256) void k_prep(
    const float* __restrict__ out_w, const float* __restrict__ new_xyz,
    unsigned short* __restrict__ owb, float* __restrict__ out0)
{
  int bid = blockIdx.x, t = threadIdx.x;
  if (bid < 16) {
    int gk = bid * 256 + t;            // (o,k): o=gk>>5, k=gk&31 ; 128*32=4096
    int o = gk >> 5, k = gk & 31;
    #pragma unroll
    for (int cb = 0; cb < 4; ++cb) {
      short8 lo, hi;
      #pragma unroll
      for (int c = 0; c < 8; ++c) lo[c] = (short)f2bf(out_w[(o*64 + cb*16 + c)*32 + k]);
      #pragma unroll
      for (int c = 0; c < 8; ++c) hi[c] = (short)f2bf(out_w[(o*64 + cb*16 + 8 + c)*32 + k]);
      *(short8*)&owb[o*2048 + cb*512 + k*16]     = lo;
      *(short8*)&owb[o*2048 + cb*512 + k*16 + 8] = hi;
    }
  } else {
    int idx = (bid - 16) * 256 + t;    // < 49152
    int b = idx / 3072, r = idx - b*3072, p = r / 3, d = r - p*3;
    out0[idx] = new_xyz[(b*3 + d)*NPP + p];
  }
}

// ---- k_xpose: F f32 [b][c][s][p] -> Fb bf16 tiles, page-dense both sides ----
// Fb tile (b,pt): u16 idx = pw*2048 + cblk*512 + sg*128 + l15*8 + j
//   where c = cblk*16+l15, s = sg*8+j, p = pt*16+pw.  Tile = 32768 u16 = 64KB.
__global__ __launch_bounds__(256) void k_xpose(
    const float* __restrict__ F, unsigned short* __restrict__ Fb)
{
  int bid = blockIdx.x;                 // 256 blocks
  // pin each b to one XCD (dispatch round-robins bid%8): b = (bid&7)*2 + hi
  int xcd = bid & 7, idx = bid >> 3;    // idx 0..31
  int b = xcd * 2 + (idx >> 4), ptq = idx & 15;   // ptq: 64-p group
  int t = threadIdx.x;
  int sg = t >> 6, l15 = (t >> 2) & 15, k4 = t & 3;  // wave=sg; lanes: 16 c x 4 p-quads

  #pragma unroll
  for (int cblk = 0; cblk < 4; ++cblk) {
    int c = cblk * 16 + l15;
    const float* src = &F[((size_t)((b*64 + c)*32) + sg*8)*NPP + ptq*64 + k4*4];
    #pragma unroll
    for (int ptl = 0; ptl < 4; ++ptl) {
      float4 v[8];
      #pragma unroll
      for (int j = 0; j < 8; ++j) v[j] = *(const float4*)&src[(size_t)j*NPP + ptl*16];
      unsigned short* tb = &Fb[(size_t)(b*64 + ptq*4 + ptl)*32768 + cblk*512 + sg*128 + l15*8];
      #pragma unroll
      for (int pwl = 0; pwl < 4; ++pwl) {
        unsigned o0 = (unsigned)f2bf(((const float*)&v[0])[pwl]) | ((unsigned)f2bf(((const float*)&v[1])[pwl]) << 16);
        unsigned o1 = (unsigned)f2bf(((const float*)&v[2])[pwl]) | ((unsigned)f2bf(((const float*)&v[3])[pwl]) << 16);
        unsigned o2 = (unsigned)f2bf(((const float*)&v[4])[pwl]) | ((unsigned)f2bf(((const float*)&v[5])[pwl]) << 16);
        unsigned o3 = (unsigned)f2bf(((const float*)&v[6])[pwl]) | ((unsigned)f2bf(((const float*)&v[7])[pwl]) << 16);
        uint4 wv = {o0, o1, o2, o3};   // j = 0..7 packed in pairs
        *(uint4*)&tb[(size_t)(k4*4 + pwl)*2048] = wv;
      }
    }
  }
}

// ---- k_main: one wg = (b, 16-point tile), 4 waves; F from Fb tiles ----
struct Smem {
  union {
    unsigned short wd[16*32*32];   // [p][k][s] bf16 = 32768 B  (wd = w * d2)
    char mm[2][16*1040];           // [buf][p][kflat-local], row = 1024B + 16B pad
  } u;
  float cst[192];                  // folded BN consts
};

__global__ __launch_bounds__(256, 4) void k_main(
    const unsigned short* __restrict__ Fb, const float* __restrict__ GX,
    const float* __restrict__ whw, const float* __restrict__ whb,
    const float* __restrict__ whg, const float* __restrict__ whbeta,
    const float* __restrict__ whm, const float* __restrict__ whv,
    const float* __restrict__ n1w, const float* __restrict__ n1b,
    const float* __restrict__ n1g, const float* __restrict__ n1beta,
    const float* __restrict__ n1m, const float* __restrict__ n1v,
    const float* __restrict__ n2w, const float* __restrict__ n2b,
    const float* __restrict__ n2g, const float* __restrict__ n2beta,
    const float* __restrict__ n2m, const float* __restrict__ n2v,
    const unsigned short* __restrict__ OWb,
    const float* __restrict__ ob, const float* __restrict__ og,
    const float* __restrict__ obeta, const float* __restrict__ om,
    const float* __restrict__ ov,
    float* __restrict__ out1)
{
  __shared__ Smem sm;
  // XCD swizzle: b = (orig&7)*2 + orig>>9 -> same b->XCD map as k_xpose (L2 reuse of Fb)
  int bid = (blockIdx.x & 7) * 128 + (blockIdx.x >> 3);
  int b = bid >> 6, p0 = (bid & 63) << 4;
  int t = threadIdx.x, lane = t & 63, w = t >> 6;
  int l15 = lane & 15, sg = lane >> 4;
  int pl0 = w * 4;

  // ---- F fragments from Fb tile: contiguous 16B/lane, 1KB/wave-inst, single page ----
  const unsigned short* ftile = &Fb[(size_t)(b*64 + (bid & 63))*32768 + sg*128 + l15*8];
  short8 af[4][4];   // [cblk][i]
  #pragma unroll
  for (int cblk = 0; cblk < 4; ++cblk)
    #pragma unroll
    for (int i = 0; i < 4; ++i)
      af[cblk][i] = *(const short8*)&ftile[(size_t)(pl0 + i)*2048 + cblk*512];

  // ---- phase 0a: gx load (s=0 zeroed per reference mutation), density->inv, max over s ----
  int pp = t >> 4, si = t & 15;        // pp = point 0..15, si -> s = 2si, 2si+1
  float gxl[2][3]; float invv[2];
  #pragma unroll
  for (int u = 0; u < 2; ++u) {
    int s = si*2 + u;
    float x = 0.f, y = 0.f, z = 0.f;
    if (s != 0) {
      const float* g = &GX[(size_t)((b*NPP + p0 + pp)*NSS + s)*3];
      x = g[0]; y = g[1]; z = g[2];
    }
    gxl[u][0]=x; gxl[u][1]=y; gxl[u][2]=z;
    float den = x + y + z;
    if (den < 1e-10f) den = 1e-10f;    // where(density < 1e-10, 1e-10, density)
    invv[u] = 1.0f / den;
  }
  float mx = fmaxf(invv[0], invv[1]);
  #pragma unroll
  for (int m = 1; m < 16; m <<= 1) mx = fmaxf(mx, __shfl_xor(mx, m, 16));

  // folded BN consts
  if (t < 32) {
    float sc = whg[t] * rsqrtf(whv[t] + 1e-5f);
    sm.cst[t]    = whw[t*3+0] * sc;
    sm.cst[32+t] = whw[t*3+1] * sc;
    sm.cst[64+t] = whw[t*3+2] * sc;
    sm.cst[96+t] = (whb[t] - whm[t]) * sc + whbeta[t];
  } else if (t < 48) {
    int i = t - 32;
    float sc = n1g[i] * rsqrtf(n1v[i] + 1e-5f);
    sm.cst[128+i] = n1w[i] * sc;
    sm.cst[144+i] = (n1b[i] - n1m[i]) * sc + n1beta[i];
  } else if (t < 64) {
    int i = t - 48;
    float sc = n2g[0] * rsqrtf(n2v[0] + 1e-5f);
    sm.cst[160+i] = n2w[i] * sc;
    if (i == 0) sm.cst[176] = (n2b[0] - n2m[0]) * sc + n2beta[0];
  }
  __syncthreads();

  // ---- phase 0b: d2 = sigmoid(MLP(ds)), weight-net w, wd = w*d2 -> LDS ----
  float d2v[2];
  #pragma unroll
  for (int u = 0; u < 2; ++u) {
    float ds = invv[u] / mx;
    float acc = sm.cst[176];
    #pragma unroll
    for (int i = 0; i < 16; ++i) {
      float d1 = fmaxf(ds * sm.cst[128+i] + sm.cst[144+i], 0.f);
      acc += d1 * sm.cst[160+i];
    }
    d2v[u] = 1.0f / (1.0f + expf(-acc));
  }
  #pragma unroll 4
  for (int k = 0; k < 32; ++k) {
    float a0 = sm.cst[k], a1 = sm.cst[32+k], a2 = sm.cst[64+k], bc = sm.cst[96+k];
    unsigned r = 0;
    #pragma unroll
    for (int u = 0; u < 2; ++u) {
      float wv = fmaxf(gxl[u][0]*a0 + gxl[u][1]*a1 + gxl[u][2]*a2 + bc, 0.f);
      wv *= d2v[u];
      r |= (unsigned)f2bf(wv) << (16*u);
    }
    *(unsigned*)&sm.u.wd[(pp*32 + k)*32 + si*2] = r;   // [p][k][s], s-pair packed
  }
  __syncthreads();

  // hoisted stage-1 B-frags (wd) for my wave's 4 points: B[k=s][n=k_out]
  short8 bfr[4][2];
  #pragma unroll
  for (int i = 0; i < 4; ++i)
    #pragma unroll
    for (int kh = 0; kh < 2; ++kh)
      bfr[i][kh] = *(const short8*)&sm.u.wd[((pl0+i)*32 + kh*16 + l15)*32 + sg*8];
  __syncthreads();   // wd dead from here; mm buffers may overwrite it

  f32x4 acc0 = {0,0,0,0}, acc1 = {0,0,0,0};
  const f32x4 z4 = {0,0,0,0};

  #pragma unroll
  for (int cblk = 0; cblk < 4; ++cblk) {
    char* mmw = sm.u.mm[cblk & 1];
    // ---- stage 1: MFMA from af (bf16 direct, no cvt), write mm ----
    {
      #pragma unroll
      for (int i = 0; i < 4; ++i) {
        f32x4 m0 = __builtin_amdgcn_mfma_f32_16x16x32_bf16(af[cblk][i], bfr[i][0], z4, 0,0,0);
        f32x4 m1 = __builtin_amdgcn_mfma_f32_16x16x32_bf16(af[cblk][i], bfr[i][1], z4, 0,0,0);
        // D: n=l15=k_out, rows c_off = sg*4+r -> kflat-local byte = k*32 + c_off*2
        char* base = mmw + (pl0+i)*1040 + l15*32 + sg*8;
        *(unsigned long long*)(base)       = pack4bf(m0);   // k = l15
        *(unsigned long long*)(base + 512) = pack4bf(m1);   // k = 16+l15
      }
    }
    __syncthreads();
    // ---- stage 2: out[o,p] += OWb[o, kflat] * mm[kflat, p], 16 K-steps this c-block ----
    {
      const unsigned short* arow0 = &OWb[(size_t)(w*32 + l15)*2048 + cblk*512 + sg*8];
      const unsigned short* arow1 = arow0 + 16*2048;
      const char* brow = mmw + l15*1040 + sg*16;
      #pragma unroll 8
      for (int tt = 0; tt < 16; ++tt) {
        short8 a0 = *(const short8*)&arow0[tt*32];
        short8 a1 = *(const short8*)&arow1[tt*32];
        short8 bb = *(const short8*)&brow[tt*64];
        acc0 = __builtin_amdgcn_mfma_f32_16x16x32_bf16(a0, bb, acc0, 0,0,0);
        acc1 = __builtin_amdgcn_mfma_f32_16x16x32_bf16(a1, bb, acc1, 0,0,0);
      }
    }
  }

  // ---- epilogue: +bias, BN, f32 store (16 lanes contiguous over p) ----
  #pragma unroll
  for (int mf = 0; mf < 2; ++mf) {
    f32x4 a = mf ? acc1 : acc0;
    #pragma unroll
    for (int r = 0; r < 4; ++r) {
      int o = w*32 + mf*16 + sg*4 + r;
      float sc = og[o] * rsqrtf(ov[o] + 1e-5f);
      float dd = (ob[o] - om[o]) * sc + obeta[o];
      out1[(size_t)(b*128 + o)*NPP + p0 + l15] = a[r] * sc + dd;
    }
  }
}

extern "C" void kernel_launch(void* const* d_in, const int* in_sizes, int n_in,
                              void* d_out, int out_size, void* d_ws, size_t ws_size,
                              hipStream_t stream) {
  (void)in_sizes; (void)n_in; (void)out_size; (void)ws_size;
  const float* new_xyz = (const float*)d_in[0];
  const float* gxyz    = (const float*)d_in[1];
  const float* gfeat   = (const float*)d_in[2];
  const float* whw     = (const float*)d_in[3];
  const float* whb     = (const float*)d_in[4];
  const float* whg     = (const float*)d_in[5];
  const float* whbeta  = (const float*)d_in[6];
  const float* whm     = (const float*)d_in[7];
  const float* whv     = (const float*)d_in[8];
  const float* n1w     = (const float*)d_in[9];
  const float* n1b     = (const float*)d_in[10];
  const float* n1g     = (const float*)d_in[11];
  const float* n1beta  = (const float*)d_in[12];
  const float* n1m     = (const float*)d_in[13];
  const float* n1v     = (const float*)d_in[14];
  const float* n2w     = (const float*)d_in[15];
  const float* n2b     = (const float*)d_in[16];
  const float* n2g     = (const float*)d_in[17];
  const float* n2beta  = (const float*)d_in[18];
  const float* n2m     = (const float*)d_in[19];
  const float* n2v     = (const float*)d_in[20];
  const float* out_w   = (const float*)d_in[21];
  const float* out_b   = (const float*)d_in[22];
  const float* out_g   = (const float*)d_in[23];
  const float* out_bt  = (const float*)d_in[24];
  const float* out_m   = (const float*)d_in[25];
  const float* out_v   = (const float*)d_in[26];

  unsigned short* owb = (unsigned short*)d_ws;   // 512 KB
  unsigned short* fb  = owb + (1u << 18);        // 64 MB bf16 tiles (ws proven >= 64.5MB in R6)
  float* out0 = (float*)d_out;                   // [16][1024][3] f32
  float* out1 = out0 + 16*1024*3;                // [16][128][1024] f32

  hipLaunchKernelGGL(k_prep,  dim3(208),  dim3(256), 0, stream, out_w, new_xyz, owb, out0);
  hipLaunchKernelGGL(k_xpose, dim3(256),  dim3(256), 0, stream, gfeat, fb);
  hipLaunchKernelGGL(k_main,  dim3(1024), dim3(256), 0, stream,
      fb, gxyz, whw, whb, whg, whbeta, whm, whv,
      n1w, n1b, n1g, n1beta, n1m, n1v,
      n2w, n2b, n2g, n2beta, n2m, n2v,
      owb, out_b, out_g, out_bt, out_m, out_v, out1);
}

// Round 10
// 88.231 us; speedup vs baseline: 1.3549x; 1.3549x over previous
//
#include <hip/hip_runtime.h>
#include <hip/hip_bf16.h>

// pointconv: density MLP + weight-net + per-point [64x32]x[32x32] + [128x2048] GEMV + BN
// B=16 NP=1024 NS=32 CIN=64 CMID=32 COUT=128. Inputs f32, outputs f32 (bf16 MFMA inside).
// R9 confirmed: page-divergent vmem is the limiter (F fix: 137->83us).
// R10: same fix for out-projection weights -> OWc chunk-major layout, every stage-2
// A-load = 64 lanes x contiguous 16B (1KB, single page). OWb old layout removed.

#define NPP 1024
#define NSS 32

typedef __attribute__((ext_vector_type(8))) short short8;
typedef __attribute__((ext_vector_type(4))) float f32x4;

__device__ __forceinline__ unsigned short f2bf(float x) {
  union { float f; unsigned u; } v; v.f = x;
  unsigned r = v.u + 0x7FFFu + ((v.u >> 16) & 1u);   // RNE
  return (unsigned short)(r >> 16);
}

__device__ __forceinline__ unsigned long long pack4bf(f32x4 v) {
  return (unsigned long long)f2bf(v[0])
       | ((unsigned long long)f2bf(v[1]) << 16)
       | ((unsigned long long)f2bf(v[2]) << 32)
       | ((unsigned long long)f2bf(v[3]) << 48);
}

// ---- k_prep: OWc chunk-major bf16 + output-0 transpose ----
// OWc u16 idx = ((w*4+cblk)*16+tt)*1024 + hi*512 + lane*8 + j   (512 KB total)
// value = out_w[(o*64 + c)*32 + k], o = w*32+hi*16+(lane&15),
//         c = cblk*16+((lane>>4)&1)*8+j, k = tt*2+(lane>>5)
__global__ __launch_bounds__(256) void k_prep(
    const float* __restrict__ out_w, const float* __restrict__ new_xyz,
    unsigned short* __restrict__ owc, float* __restrict__ out0)
{
  int bid = blockIdx.x, t = threadIdx.x;
  if (bid < 128) {
    int gid = bid * 256 + t;           // 32768 = 512 chunks x 64 lanes
    int lane = gid & 63, ci = gid >> 6;
    int hi = ci & 1, tt = (ci >> 1) & 15, cblk = (ci >> 5) & 3, w = ci >> 7;
    int sg = lane >> 4, l15 = lane & 15;
    int o = w*32 + hi*16 + l15;
    int k = tt*2 + (sg >> 1);
    int cbase = cblk*16 + (sg & 1)*8;
    short8 vv;
    #pragma unroll
    for (int j = 0; j < 8; ++j)
      vv[j] = (short)f2bf(out_w[(o*64 + cbase + j)*32 + k]);
    *(short8*)&owc[(size_t)gid * 8] = vv;
  } else {
    int idx = (bid - 128) * 256 + t;   // < 49152
    int b = idx / 3072, r = idx - b*3072, p = r / 3, d = r - p*3;
    out0[idx] = new_xyz[(b*3 + d)*NPP + p];
  }
}

// ---- k_xpose: F f32 [b][c][s][p] -> Fb bf16 tiles, page-dense both sides ----
// Fb tile (b,pt): u16 idx = pw*2048 + cblk*512 + sg*128 + l15*8 + j
//   where c = cblk*16+l15, s = sg*8+j, p = pt*16+pw.  Tile = 32768 u16 = 64KB.
__global__ __launch_bounds__(256) void k_xpose(
    const float* __restrict__ F, unsigned short* __restrict__ Fb)
{
  int bid = blockIdx.x;                 // 256 blocks
  int xcd = bid & 7, idx = bid >> 3;    // pin each b to one XCD
  int b = xcd * 2 + (idx >> 4), ptq = idx & 15;
  int t = threadIdx.x;
  int sg = t >> 6, l15 = (t >> 2) & 15, k4 = t & 3;

  #pragma unroll
  for (int cblk = 0; cblk < 4; ++cblk) {
    int c = cblk * 16 + l15;
    const float* src = &F[((size_t)((b*64 + c)*32) + sg*8)*NPP + ptq*64 + k4*4];
    #pragma unroll
    for (int ptl = 0; ptl < 4; ++ptl) {
      float4 v[8];
      #pragma unroll
      for (int j = 0; j < 8; ++j) v[j] = *(const float4*)&src[(size_t)j*NPP + ptl*16];
      unsigned short* tb = &Fb[(size_t)(b*64 + ptq*4 + ptl)*32768 + cblk*512 + sg*128 + l15*8];
      #pragma unroll
      for (int pwl = 0; pwl < 4; ++pwl) {
        unsigned o0 = (unsigned)f2bf(((const float*)&v[0])[pwl]) | ((unsigned)f2bf(((const float*)&v[1])[pwl]) << 16);
        unsigned o1 = (unsigned)f2bf(((const float*)&v[2])[pwl]) | ((unsigned)f2bf(((const float*)&v[3])[pwl]) << 16);
        unsigned o2 = (unsigned)f2bf(((const float*)&v[4])[pwl]) | ((unsigned)f2bf(((const float*)&v[5])[pwl]) << 16);
        unsigned o3 = (unsigned)f2bf(((const float*)&v[6])[pwl]) | ((unsigned)f2bf(((const float*)&v[7])[pwl]) << 16);
        uint4 wv = {o0, o1, o2, o3};
        *(uint4*)&tb[(size_t)(k4*4 + pwl)*2048] = wv;
      }
    }
  }
}

// ---- k_main: one wg = (b, 16-point tile), 4 waves; F from Fb, weights from OWc ----
struct Smem {
  union {
    unsigned short wd[16*32*32];   // [p][k][s] bf16 = 32768 B  (wd = w * d2)
    char mm[2][16*1040];           // [buf][p][kflat-local], row = 1024B + 16B pad
  } u;
  float cst[192];                  // folded BN consts
};

__global__ __launch_bounds__(256, 4) void k_main(
    const unsigned short* __restrict__ Fb, const float* __restrict__ GX,
    const float* __restrict__ whw, const float* __restrict__ whb,
    const float* __restrict__ whg, const float* __restrict__ whbeta,
    const float* __restrict__ whm, const float* __restrict__ whv,
    const float* __restrict__ n1w, const float* __restrict__ n1b,
    const float* __restrict__ n1g, const float* __restrict__ n1beta,
    const float* __restrict__ n1m, const float* __restrict__ n1v,
    const float* __restrict__ n2w, const float* __restrict__ n2b,
    const float* __restrict__ n2g, const float* __restrict__ n2beta,
    const float* __restrict__ n2m, const float* __restrict__ n2v,
    const unsigned short* __restrict__ OWc,
    const float* __restrict__ ob, const float* __restrict__ og,
    const float* __restrict__ obeta, const float* __restrict__ om,
    const float* __restrict__ ov,
    float* __restrict__ out1)
{
  __shared__ Smem sm;
  // XCD swizzle matching k_xpose's b->XCD pinning (L2 reuse of Fb)
  int bid = (blockIdx.x & 7) * 128 + (blockIdx.x >> 3);
  int b = bid >> 6, p0 = (bid & 63) << 4;
  int t = threadIdx.x, lane = t & 63, w = t >> 6;
  int l15 = lane & 15, sg = lane >> 4;
  int pl0 = w * 4;

  // ---- F fragments from Fb tile: contiguous 16B/lane, 1KB/wave-inst, single page ----
  const unsigned short* ftile = &Fb[(size_t)(b*64 + (bid & 63))*32768 + sg*128 + l15*8];
  short8 af[4][4];   // [cblk][i]
  #pragma unroll
  for (int cblk = 0; cblk < 4; ++cblk)
    #pragma unroll
    for (int i = 0; i < 4; ++i)
      af[cblk][i] = *(const short8*)&ftile[(size_t)(pl0 + i)*2048 + cblk*512];

  // ---- phase 0a: gx load (s=0 zeroed per reference mutation), density->inv, max over s ----
  int pp = t >> 4, si = t & 15;
  float gxl[2][3]; float invv[2];
  #pragma unroll
  for (int u = 0; u < 2; ++u) {
    int s = si*2 + u;
    float x = 0.f, y = 0.f, z = 0.f;
    if (s != 0) {
      const float* g = &GX[(size_t)((b*NPP + p0 + pp)*NSS + s)*3];
      x = g[0]; y = g[1]; z = g[2];
    }
    gxl[u][0]=x; gxl[u][1]=y; gxl[u][2]=z;
    float den = x + y + z;
    if (den < 1e-10f) den = 1e-10f;
    invv[u] = 1.0f / den;
  }
  float mx = fmaxf(invv[0], invv[1]);
  #pragma unroll
  for (int m = 1; m < 16; m <<= 1) mx = fmaxf(mx, __shfl_xor(mx, m, 16));

  // folded BN consts
  if (t < 32) {
    float sc = whg[t] * rsqrtf(whv[t] + 1e-5f);
    sm.cst[t]    = whw[t*3+0] * sc;
    sm.cst[32+t] = whw[t*3+1] * sc;
    sm.cst[64+t] = whw[t*3+2] * sc;
    sm.cst[96+t] = (whb[t] - whm[t]) * sc + whbeta[t];
  } else if (t < 48) {
    int i = t - 32;
    float sc = n1g[i] * rsqrtf(n1v[i] + 1e-5f);
    sm.cst[128+i] = n1w[i] * sc;
    sm.cst[144+i] = (n1b[i] - n1m[i]) * sc + n1beta[i];
  } else if (t < 64) {
    int i = t - 48;
    float sc = n2g[0] * rsqrtf(n2v[0] + 1e-5f);
    sm.cst[160+i] = n2w[i] * sc;
    if (i == 0) sm.cst[176] = (n2b[0] - n2m[0]) * sc + n2beta[0];
  }
  __syncthreads();

  // ---- phase 0b: d2 = sigmoid(MLP(ds)), weight-net w, wd = w*d2 -> LDS ----
  float d2v[2];
  #pragma unroll
  for (int u = 0; u < 2; ++u) {
    float ds = invv[u] / mx;
    float acc = sm.cst[176];
    #pragma unroll
    for (int i = 0; i < 16; ++i) {
      float d1 = fmaxf(ds * sm.cst[128+i] + sm.cst[144+i], 0.f);
      acc += d1 * sm.cst[160+i];
    }
    d2v[u] = 1.0f / (1.0f + expf(-acc));
  }
  #pragma unroll 4
  for (int k = 0; k < 32; ++k) {
    float a0 = sm.cst[k], a1 = sm.cst[32+k], a2 = sm.cst[64+k], bc = sm.cst[96+k];
    unsigned r = 0;
    #pragma unroll
    for (int u = 0; u < 2; ++u) {
      float wv = fmaxf(gxl[u][0]*a0 + gxl[u][1]*a1 + gxl[u][2]*a2 + bc, 0.f);
      wv *= d2v[u];
      r |= (unsigned)f2bf(wv) << (16*u);
    }
    *(unsigned*)&sm.u.wd[(pp*32 + k)*32 + si*2] = r;
  }
  __syncthreads();

  // hoisted stage-1 B-frags (wd) for my wave's 4 points: B[k=s][n=k_out]
  short8 bfr[4][2];
  #pragma unroll
  for (int i = 0; i < 4; ++i)
    #pragma unroll
    for (int kh = 0; kh < 2; ++kh)
      bfr[i][kh] = *(const short8*)&sm.u.wd[((pl0+i)*32 + kh*16 + l15)*32 + sg*8];
  __syncthreads();   // wd dead from here; mm buffers may overwrite it

  f32x4 acc0 = {0,0,0,0}, acc1 = {0,0,0,0};
  const f32x4 z4 = {0,0,0,0};

  #pragma unroll
  for (int cblk = 0; cblk < 4; ++cblk) {
    char* mmw = sm.u.mm[cblk & 1];
    // ---- stage 1: MFMA from af (bf16 direct), write mm ----
    {
      #pragma unroll
      for (int i = 0; i < 4; ++i) {
        f32x4 m0 = __builtin_amdgcn_mfma_f32_16x16x32_bf16(af[cblk][i], bfr[i][0], z4, 0,0,0);
        f32x4 m1 = __builtin_amdgcn_mfma_f32_16x16x32_bf16(af[cblk][i], bfr[i][1], z4, 0,0,0);
        char* base = mmw + (pl0+i)*1040 + l15*32 + sg*8;
        *(unsigned long long*)(base)       = pack4bf(m0);   // k = l15
        *(unsigned long long*)(base + 512) = pack4bf(m1);   // k = 16+l15
      }
    }
    __syncthreads();
    // ---- stage 2: OWc chunk-major loads (1KB line-dense per inst) ----
    {
      const unsigned short* ac = &OWc[(size_t)((w*4 + cblk)*16)*1024 + lane*8];
      const char* brow = mmw + l15*1040 + sg*16;
      #pragma unroll 8
      for (int tt = 0; tt < 16; ++tt) {
        short8 a0 = *(const short8*)&ac[tt*1024];
        short8 a1 = *(const short8*)&ac[tt*1024 + 512];
        short8 bb = *(const short8*)&brow[tt*64];
        acc0 = __builtin_amdgcn_mfma_f32_16x16x32_bf16(a0, bb, acc0, 0,0,0);
        acc1 = __builtin_amdgcn_mfma_f32_16x16x32_bf16(a1, bb, acc1, 0,0,0);
      }
    }
  }

  // ---- epilogue: +bias, BN, f32 store (16 lanes contiguous over p) ----
  #pragma unroll
  for (int mf = 0; mf < 2; ++mf) {
    f32x4 a = mf ? acc1 : acc0;
    #pragma unroll
    for (int r = 0; r < 4; ++r) {
      int o = w*32 + mf*16 + sg*4 + r;
      float sc = og[o] * rsqrtf(ov[o] + 1e-5f);
      float dd = (ob[o] - om[o]) * sc + obeta[o];
      out1[(size_t)(b*128 + o)*NPP + p0 + l15] = a[r] * sc + dd;
    }
  }
}

extern "C" void kernel_launch(void* const* d_in, const int* in_sizes, int n_in,
                              void* d_out, int out_size, void* d_ws, size_t ws_size,
                              hipStream_t stream) {
  (void)in_sizes; (void)n_in; (void)out_size; (void)ws_size;
  const float* new_xyz = (const float*)d_in[0];
  const float* gxyz    = (const float*)d_in[1];
  const float* gfeat   = (const float*)d_in[2];
  const float* whw     = (const float*)d_in[3];
  const float* whb     = (const float*)d_in[4];
  const float* whg     = (const float*)d_in[5];
  const float* whbeta  = (const float*)d_in[6];
  const float* whm     = (const float*)d_in[7];
  const float* whv     = (const float*)d_in[8];
  const float* n1w     = (const float*)d_in[9];
  const float* n1b     = (const float*)d_in[10];
  const float* n1g     = (const float*)d_in[11];
  const float* n1beta  = (const float*)d_in[12];
  const float* n1m     = (const float*)d_in[13];
  const float* n1v     = (const float*)d_in[14];
  const float* n2w     = (const float*)d_in[15];
  const float* n2b     = (const float*)d_in[16];
  const float* n2g     = (const float*)d_in[17];
  const float* n2beta  = (const float*)d_in[18];
  const float* n2m     = (const float*)d_in[19];
  const float* n2v     = (const float*)d_in[20];
  const float* out_w   = (const float*)d_in[21];
  const float* out_b   = (const float*)d_in[22];
  const float* out_g   = (const float*)d_in[23];
  const float* out_bt  = (const float*)d_in[24];
  const float* out_m   = (const float*)d_in[25];
  const float* out_v   = (const float*)d_in[26];

  unsigned short* owc = (unsigned short*)d_ws;   // 512 KB chunk-major weights
  unsigned short* fb  = owc + (1u << 18);        // 64 MB bf16 F tiles
  float* out0 = (float*)d_out;                   // [16][1024][3] f32
  float* out1 = out0 + 16*1024*3;                // [16][128][1024] f32

  hipLaunchKernelGGL(k_prep,  dim3(320),  dim3(256), 0, stream, out_w, new_xyz, owc, out0);
  hipLaunchKernelGGL(k_xpose, dim3(256),  dim3(256), 0, stream, gfeat, fb);
  hipLaunchKernelGGL(k_main,  dim3(1024), dim3(256), 0, stream,
      fb, gxyz, whw, whb, whg, whbeta, whm, whv,
      n1w, n1b, n1g, n1beta, n1m, n1v,
      n2w, n2b, n2g, n2beta, n2m, n2v,
      owc, out_b, out_g, out_bt, out_m, out_v, out1);
}

// Round 11
// 87.018 us; speedup vs baseline: 1.3738x; 1.0139x over previous
//
#include <hip/hip_runtime.h>
#include <hip/hip_bf16.h>

// pointconv: density MLP + weight-net + per-point [64x32]x[32x32] + [128x2048] GEMV + BN
// B=16 NP=1024 NS=32 CIN=64 CMID=32 COUT=128. Inputs f32, outputs f32 (bf16 MFMA inside).
// R11: 64-point blocks (8 waves, 512 thr): OWc L2 traffic /4, A/B-balanced stage-2
// (2A x 2B x 4 MFMA per tt), one-shot phase0 (gxd tile), per-cblk stage1->barrier->stage2,
// mm XOR-swizzle ((row&15)<<4). wd is strictly intra-wave (no barrier).

#define NPP 1024
#define NSS 32

typedef __attribute__((ext_vector_type(8))) short short8;
typedef __attribute__((ext_vector_type(4))) float f32x4;

__device__ __forceinline__ unsigned short f2bf(float x) {
  union { float f; unsigned u; } v; v.f = x;
  unsigned r = v.u + 0x7FFFu + ((v.u >> 16) & 1u);   // RNE
  return (unsigned short)(r >> 16);
}

__device__ __forceinline__ unsigned long long pack4bf(f32x4 v) {
  return (unsigned long long)f2bf(v[0])
       | ((unsigned long long)f2bf(v[1]) << 16)
       | ((unsigned long long)f2bf(v[2]) << 32)
       | ((unsigned long long)f2bf(v[3]) << 48);
}

// ---- k_prep: OWc chunk-major bf16 + output-0 transpose (unchanged from R10) ----
__global__ __launch_bounds__(256) void k_prep(
    const float* __restrict__ out_w, const float* __restrict__ new_xyz,
    unsigned short* __restrict__ owc, float* __restrict__ out0)
{
  int bid = blockIdx.x, t = threadIdx.x;
  if (bid < 128) {
    int gid = bid * 256 + t;           // 32768 = 512 chunks x 64 lanes
    int lane = gid & 63, ci = gid >> 6;
    int hi = ci & 1, tt = (ci >> 1) & 15, cblk = (ci >> 5) & 3, w = ci >> 7;
    int sg = lane >> 4, l15 = lane & 15;
    int o = w*32 + hi*16 + l15;
    int k = tt*2 + (sg >> 1);
    int cbase = cblk*16 + (sg & 1)*8;
    short8 vv;
    #pragma unroll
    for (int j = 0; j < 8; ++j)
      vv[j] = (short)f2bf(out_w[(o*64 + cbase + j)*32 + k]);
    *(short8*)&owc[(size_t)gid * 8] = vv;
  } else {
    int idx = (bid - 128) * 256 + t;   // < 49152
    int b = idx / 3072, r = idx - b*3072, p = r / 3, d = r - p*3;
    out0[idx] = new_xyz[(b*3 + d)*NPP + p];
  }
}

// ---- k_xpose: F f32 [b][c][s][p] -> Fb bf16 tiles (unchanged from R10) ----
__global__ __launch_bounds__(256) void k_xpose(
    const float* __restrict__ F, unsigned short* __restrict__ Fb)
{
  int bid = blockIdx.x;                 // 256 blocks
  int xcd = bid & 7, idx = bid >> 3;    // pin each b to one XCD
  int b = xcd * 2 + (idx >> 4), ptq = idx & 15;
  int t = threadIdx.x;
  int sg = t >> 6, l15 = (t >> 2) & 15, k4 = t & 3;

  #pragma unroll
  for (int cblk = 0; cblk < 4; ++cblk) {
    int c = cblk * 16 + l15;
    const float* src = &F[((size_t)((b*64 + c)*32) + sg*8)*NPP + ptq*64 + k4*4];
    #pragma unroll
    for (int ptl = 0; ptl < 4; ++ptl) {
      float4 v[8];
      #pragma unroll
      for (int j = 0; j < 8; ++j) v[j] = *(const float4*)&src[(size_t)j*NPP + ptl*16];
      unsigned short* tb = &Fb[(size_t)(b*64 + ptq*4 + ptl)*32768 + cblk*512 + sg*128 + l15*8];
      #pragma unroll
      for (int pwl = 0; pwl < 4; ++pwl) {
        unsigned o0 = (unsigned)f2bf(((const float*)&v[0])[pwl]) | ((unsigned)f2bf(((const float*)&v[1])[pwl]) << 16);
        unsigned o1 = (unsigned)f2bf(((const float*)&v[2])[pwl]) | ((unsigned)f2bf(((const float*)&v[3])[pwl]) << 16);
        unsigned o2 = (unsigned)f2bf(((const float*)&v[4])[pwl]) | ((unsigned)f2bf(((const float*)&v[5])[pwl]) << 16);
        unsigned o3 = (unsigned)f2bf(((const float*)&v[6])[pwl]) | ((unsigned)f2bf(((const float*)&v[7])[pwl]) << 16);
        uint4 wv = {o0, o1, o2, o3};
        *(uint4*)&tb[(size_t)(k4*4 + pwl)*2048] = wv;
      }
    }
  }
}

// ---- k_main v2: one wg = (b, 64-point tile), 8 waves (512 thr) ----
struct Smem2 {
  float gxd[64*32*4];            // (x,y,z,d2) per (p,s)        32 KB
  unsigned short wd[16*32*32];   // wd, per-wave 2-point slices 32 KB
  char mm[64*1024];              // [p][this-cblk kflat] swizz  64 KB
  float cst[192];
};

__global__ __launch_bounds__(512, 1) void k_main(
    const unsigned short* __restrict__ Fb, const float* __restrict__ GX,
    const float* __restrict__ whw, const float* __restrict__ whb,
    const float* __restrict__ whg, const float* __restrict__ whbeta,
    const float* __restrict__ whm, const float* __restrict__ whv,
    const float* __restrict__ n1w, const float* __restrict__ n1b,
    const float* __restrict__ n1g, const float* __restrict__ n1beta,
    const float* __restrict__ n1m, const float* __restrict__ n1v,
    const float* __restrict__ n2w, const float* __restrict__ n2b,
    const float* __restrict__ n2g, const float* __restrict__ n2beta,
    const float* __restrict__ n2m, const float* __restrict__ n2v,
    const unsigned short* __restrict__ OWc,
    const float* __restrict__ ob, const float* __restrict__ og,
    const float* __restrict__ obeta, const float* __restrict__ om,
    const float* __restrict__ ov,
    float* __restrict__ out1)
{
  __shared__ Smem2 sm;
  int xcd = blockIdx.x & 7, idx = blockIdx.x >> 3;   // same b->XCD pinning as k_xpose
  int b = xcd*2 + (idx >> 4), pt64 = idx & 15;
  int p0 = pt64 * 64;
  int t = threadIdx.x, w = t >> 6, lane = t & 63;
  int l15 = lane & 15, sg = lane >> 4;

  // ---- phase 0a: gx (3 aligned float4/thread), density, d2 for all 64 points ----
  int pp8 = t >> 3, si8 = t & 7;
  const float* g = &GX[(size_t)(b*NPP + p0 + pp8)*96 + si8*12];
  float4 f0 = *(const float4*)g;
  float4 f1 = *(const float4*)(g + 4);
  float4 f2 = *(const float4*)(g + 8);

  if (t < 32) {
    float sc = whg[t] * rsqrtf(whv[t] + 1e-5f);
    sm.cst[t]    = whw[t*3+0] * sc;
    sm.cst[32+t] = whw[t*3+1] * sc;
    sm.cst[64+t] = whw[t*3+2] * sc;
    sm.cst[96+t] = (whb[t] - whm[t]) * sc + whbeta[t];
  } else if (t < 48) {
    int i = t - 32;
    float sc = n1g[i] * rsqrtf(n1v[i] + 1e-5f);
    sm.cst[128+i] = n1w[i] * sc;
    sm.cst[144+i] = (n1b[i] - n1m[i]) * sc + n1beta[i];
  } else if (t < 64) {
    int i = t - 48;
    float sc = n2g[0] * rsqrtf(n2v[0] + 1e-5f);
    sm.cst[160+i] = n2w[i] * sc;
    if (i == 0) sm.cst[176] = (n2b[0] - n2m[0]) * sc + n2beta[0];
  }
  __syncthreads();

  {
    float xs[4], ys[4], zs[4], inv[4];
    xs[0]=f0.x; ys[0]=f0.y; zs[0]=f0.z;
    xs[1]=f0.w; ys[1]=f1.x; zs[1]=f1.y;
    xs[2]=f1.z; ys[2]=f1.w; zs[2]=f2.x;
    xs[3]=f2.y; ys[3]=f2.z; zs[3]=f2.w;
    if (si8 == 0) { xs[0]=0.f; ys[0]=0.f; zs[0]=0.f; }   // s=0 zeroed per reference
    float mx = 0.f;
    #pragma unroll
    for (int u = 0; u < 4; ++u) {
      float den = xs[u] + ys[u] + zs[u];
      if (den < 1e-10f) den = 1e-10f;
      inv[u] = 1.0f / den;
      mx = fmaxf(mx, inv[u]);
    }
    #pragma unroll
    for (int m = 1; m < 8; m <<= 1) mx = fmaxf(mx, __shfl_xor(mx, m, 8));
    #pragma unroll
    for (int u = 0; u < 4; ++u) {
      float ds = inv[u] / mx;
      float acc = sm.cst[176];
      #pragma unroll
      for (int i = 0; i < 16; ++i) {
        float d1 = fmaxf(ds * sm.cst[128+i] + sm.cst[144+i], 0.f);
        acc += d1 * sm.cst[160+i];
      }
      float d2 = 1.0f / (1.0f + expf(-acc));
      float4 st = {xs[u], ys[u], zs[u], d2};
      *(float4*)&sm.gxd[(size_t)(pp8*32 + si8*4 + u)*4] = st;
    }
  }
  __syncthreads();

  // ---- phase 0b (all 4 pgs at once is impossible for wd; do per-wave 2 points x 4 pgs):
  // Each wave computes wd + hoists bfr + loads af for its OWN 8 points (2 per pg).
  // wd slice [ppL = w*2, w*2+1] is private to wave w -> no barriers.
  const f32x4 z4 = {0,0,0,0};
  int phKh = (lane >> 4) & 1;
  int phPp = w*2 + (lane >> 5);        // wd-writer role: point (pg-local)
  int phSi = lane & 15;
  int ppA = w*2, ppB = w*2 + 1;
  int c0 = l15*32 + sg*8;

  short8 afA[4][4], afB[4][4];         // [pg][cblk]
  short8 bfrA[4][2], bfrB[4][2];       // [pg][kh]
  #pragma unroll
  for (int pg = 0; pg < 4; ++pg) {
    const unsigned short* ft = &Fb[(size_t)(b*64 + pt64*4 + pg)*32768 + sg*128 + l15*8];
    #pragma unroll
    for (int cblk = 0; cblk < 4; ++cblk) {
      afA[pg][cblk] = *(const short8*)&ft[(size_t)ppA*2048 + cblk*512];
      afB[pg][cblk] = *(const short8*)&ft[(size_t)ppB*2048 + cblk*512];
    }
    const float4 ga = *(const float4*)&sm.gxd[(size_t)((pg*16 + phPp)*32 + phSi*2)*4];
    const float4 gb = *(const float4*)&sm.gxd[(size_t)((pg*16 + phPp)*32 + phSi*2 + 1)*4];
    #pragma unroll
    for (int ki = 0; ki < 16; ++ki) {
      int k = phKh*16 + ki;
      float a0 = sm.cst[k], a1 = sm.cst[32+k], a2 = sm.cst[64+k], bc = sm.cst[96+k];
      float w0 = fmaxf(ga.x*a0 + ga.y*a1 + ga.z*a2 + bc, 0.f) * ga.w;
      float w1 = fmaxf(gb.x*a0 + gb.y*a1 + gb.z*a2 + bc, 0.f) * gb.w;
      unsigned r = (unsigned)f2bf(w0) | ((unsigned)f2bf(w1) << 16);
      *(unsigned*)&sm.wd[(phPp*32 + k)*32 + phSi*2] = r;
    }
    #pragma unroll
    for (int kh = 0; kh < 2; ++kh) {   // intra-wave RAW on sm.wd
      bfrA[pg][kh] = *(const short8*)&sm.wd[(ppA*32 + kh*16 + l15)*32 + sg*8];
      bfrB[pg][kh] = *(const short8*)&sm.wd[(ppB*32 + kh*16 + l15)*32 + sg*8];
    }
  }

  // ---- main loop: per cblk: stage1(all 64 p) -> barrier -> stage2 -> barrier ----
  int w4 = w & 3, gp0 = (w >> 2) * 2;
  f32x4 acc00 = {0,0,0,0}, acc10 = {0,0,0,0}, acc01 = {0,0,0,0}, acc11 = {0,0,0,0};
  int rowG0 = gp0*16 + l15, rowG1 = (gp0+1)*16 + l15;
  unsigned sw0 = (rowG0 & 15) << 4, sw1 = (rowG1 & 15) << 4;
  const char* bbase0 = sm.mm + rowG0*1024;
  const char* bbase1 = sm.mm + rowG1*1024;

  #pragma unroll
  for (int cblk = 0; cblk < 4; ++cblk) {
    #pragma unroll
    for (int pg = 0; pg < 4; ++pg) {
      f32x4 mA0 = __builtin_amdgcn_mfma_f32_16x16x32_bf16(afA[pg][cblk], bfrA[pg][0], z4, 0,0,0);
      f32x4 mA1 = __builtin_amdgcn_mfma_f32_16x16x32_bf16(afA[pg][cblk], bfrA[pg][1], z4, 0,0,0);
      f32x4 mB0 = __builtin_amdgcn_mfma_f32_16x16x32_bf16(afB[pg][cblk], bfrB[pg][0], z4, 0,0,0);
      f32x4 mB1 = __builtin_amdgcn_mfma_f32_16x16x32_bf16(afB[pg][cblk], bfrB[pg][1], z4, 0,0,0);
      int rowA = pg*16 + ppA, rowB = pg*16 + ppB;
      unsigned swA = (rowA & 15) << 4, swB = (rowB & 15) << 4;
      char* bA = sm.mm + rowA*1024;
      char* bB = sm.mm + rowB*1024;
      *(unsigned long long*)(bA + ((c0      ) ^ swA)) = pack4bf(mA0);
      *(unsigned long long*)(bA + ((c0 + 512) ^ swA)) = pack4bf(mA1);
      *(unsigned long long*)(bB + ((c0      ) ^ swB)) = pack4bf(mB0);
      *(unsigned long long*)(bB + ((c0 + 512) ^ swB)) = pack4bf(mB1);
    }
    __syncthreads();
    {
      const unsigned short* ac = &OWc[(size_t)((w4*4 + cblk)*16)*1024 + lane*8];
      #pragma unroll 8
      for (int tt = 0; tt < 16; ++tt) {
        short8 a0 = *(const short8*)&ac[tt*1024];
        short8 a1 = *(const short8*)&ac[tt*1024 + 512];
        int col = sg*16 + tt*64;
        short8 b0 = *(const short8*)(bbase0 + (col ^ sw0));
        short8 b1 = *(const short8*)(bbase1 + (col ^ sw1));
        acc00 = __builtin_amdgcn_mfma_f32_16x16x32_bf16(a0, b0, acc00, 0,0,0);
        acc10 = __builtin_amdgcn_mfma_f32_16x16x32_bf16(a1, b0, acc10, 0,0,0);
        acc01 = __builtin_amdgcn_mfma_f32_16x16x32_bf16(a0, b1, acc01, 0,0,0);
        acc11 = __builtin_amdgcn_mfma_f32_16x16x32_bf16(a1, b1, acc11, 0,0,0);
      }
    }
    __syncthreads();
  }

  // ---- epilogue: +bias, BN, f32 store ----
  #pragma unroll
  for (int hi = 0; hi < 2; ++hi)
    #pragma unroll
    for (int gg = 0; gg < 2; ++gg) {
      f32x4 a = hi ? (gg ? acc11 : acc10) : (gg ? acc01 : acc00);
      #pragma unroll
      for (int r = 0; r < 4; ++r) {
        int o = w4*32 + hi*16 + sg*4 + r;
        float sc = og[o] * rsqrtf(ov[o] + 1e-5f);
        float dd = (ob[o] - om[o]) * sc + obeta[o];
        out1[(size_t)(b*128 + o)*NPP + p0 + (gp0+gg)*16 + l15] = a[r] * sc + dd;
      }
    }
}

extern "C" void kernel_launch(void* const* d_in, const int* in_sizes, int n_in,
                              void* d_out, int out_size, void* d_ws, size_t ws_size,
                              hipStream_t stream) {
  (void)in_sizes; (void)n_in; (void)out_size; (void)ws_size;
  const float* new_xyz = (const float*)d_in[0];
  const float* gxyz    = (const float*)d_in[1];
  const float* gfeat   = (const float*)d_in[2];
  const float* whw     = (const float*)d_in[3];
  const float* whb     = (const float*)d_in[4];
  const float* whg     = (const float*)d_in[5];
  const float* whbeta  = (const float*)d_in[6];
  const float* whm     = (const float*)d_in[7];
  const float* whv     = (const float*)d_in[8];
  const float* n1w     = (const float*)d_in[9];
  const float* n1b     = (const float*)d_in[10];
  const float* n1g     = (const float*)d_in[11];
  const float* n1beta  = (const float*)d_in[12];
  const float* n1m     = (const float*)d_in[13];
  const float* n1v     = (const float*)d_in[14];
  const float* n2w     = (const float*)d_in[15];
  const float* n2b     = (const float*)d_in[16];
  const float* n2g     = (const float*)d_in[17];
  const float* n2beta  = (const float*)d_in[18];
  const float* n2m     = (const float*)d_in[19];
  const float* n2v     = (const float*)d_in[20];
  const float* out_w   = (const float*)d_in[21];
  const float* out_b   = (const float*)d_in[22];
  const float* out_g   = (const float*)d_in[23];
  const float* out_bt  = (const float*)d_in[24];
  const float* out_m   = (const float*)d_in[25];
  const float* out_v   = (const float*)d_in[26];

  unsigned short* owc = (unsigned short*)d_ws;   // 512 KB chunk-major weights
  unsigned short* fb  = owc + (1u << 18);        // 64 MB bf16 F tiles
  float* out0 = (float*)d_out;                   // [16][1024][3] f32
  float* out1 = out0 + 16*1024*3;                // [16][128][1024] f32

  hipLaunchKernelGGL(k_prep,  dim3(320), dim3(256), 0, stream, out_w, new_xyz, owc, out0);
  hipLaunchKernelGGL(k_xpose, dim3(256), dim3(256), 0, stream, gfeat, fb);
  hipLaunchKernelGGL(k_main,  dim3(256), dim3(512), 0, stream,
      fb, gxyz, whw, whb, whg, whbeta, whm, whv,
      n1w, n1b, n1g, n1beta, n1m, n1v,
      n2w, n2b, n2g, n2beta, n2m, n2v,
      owc, out_b, out_g, out_bt, out_m, out_v, out1);
}

// Round 12
// 70.945 us; speedup vs baseline: 1.6850x; 1.2266x over previous
//
#include <hip/hip_runtime.h>
#include <hip/hip_bf16.h>

// pointconv: density MLP + weight-net + per-point [64x32]x[32x32] + [128x2048] GEMV + BN
// B=16 NP=1024 NS=32 CIN=64 CMID=32 COUT=128. Inputs f32, outputs f32 (bf16 MFMA inside).
// R12: fuse the F-relayout INTO k_main (kills the 64MB Fb write + 64MB read round trip).
// Per cblk: stage F (k_xpose's 16-page/64B pattern) -> bf16 -> p-XOR-swizzled LDS fstage
// (aliases dead gxd/wd), af reads are 1KB-dense b128. F loads for cblk+1 issue under
// stage1 (T14). 2 kernels total.

#define NPP 1024

typedef __attribute__((ext_vector_type(8))) short short8;
typedef __attribute__((ext_vector_type(4))) float f32x4;

__device__ __forceinline__ unsigned short f2bf(float x) {
  union { float f; unsigned u; } v; v.f = x;
  unsigned r = v.u + 0x7FFFu + ((v.u >> 16) & 1u);   // RNE
  return (unsigned short)(r >> 16);
}

__device__ __forceinline__ unsigned long long pack4bf(f32x4 v) {
  return (unsigned long long)f2bf(v[0])
       | ((unsigned long long)f2bf(v[1]) << 16)
       | ((unsigned long long)f2bf(v[2]) << 32)
       | ((unsigned long long)f2bf(v[3]) << 48);
}

// ---- k_prep: OWc chunk-major bf16 + output-0 transpose (unchanged from R10) ----
__global__ __launch_bounds__(256) void k_prep(
    const float* __restrict__ out_w, const float* __restrict__ new_xyz,
    unsigned short* __restrict__ owc, float* __restrict__ out0)
{
  int bid = blockIdx.x, t = threadIdx.x;
  if (bid < 128) {
    int gid = bid * 256 + t;           // 32768 = 512 chunks x 64 lanes
    int lane = gid & 63, ci = gid >> 6;
    int hi = ci & 1, tt = (ci >> 1) & 15, cblk = (ci >> 5) & 3, w = ci >> 7;
    int sg = lane >> 4, l15 = lane & 15;
    int o = w*32 + hi*16 + l15;
    int k = tt*2 + (sg >> 1);
    int cbase = cblk*16 + (sg & 1)*8;
    short8 vv;
    #pragma unroll
    for (int j = 0; j < 8; ++j)
      vv[j] = (short)f2bf(out_w[(o*64 + cbase + j)*32 + k]);
    *(short8*)&owc[(size_t)gid * 8] = vv;
  } else {
    int idx = (bid - 128) * 256 + t;   // < 49152
    int b = idx / 3072, r = idx - b*3072, p = r / 3, d = r - p*3;
    out0[idx] = new_xyz[(b*3 + d)*NPP + p];
  }
}

// ---- k_main v3: one wg = (b, 64-point tile), 8 waves; F staged per-cblk in LDS ----
struct Smem3 {
  union {
    struct {
      float gxd[64*32*4];            // (x,y,z,d2) per (p,s)   32 KB
      unsigned short wd[16*32*32];   // wd per-wave slices     32 KB
    } ph0;
    unsigned short fs[32768];        // per-cblk F tile (swizzled)  64 KB
  } u;
  char mm[64*1024];                  // [p][kflat-this-cblk] swizz  64 KB
  float cst[192];
};

__global__ __launch_bounds__(512, 1) void k_main(
    const float* __restrict__ F, const float* __restrict__ GX,
    const float* __restrict__ whw, const float* __restrict__ whb,
    const float* __restrict__ whg, const float* __restrict__ whbeta,
    const float* __restrict__ whm, const float* __restrict__ whv,
    const float* __restrict__ n1w, const float* __restrict__ n1b,
    const float* __restrict__ n1g, const float* __restrict__ n1beta,
    const float* __restrict__ n1m, const float* __restrict__ n1v,
    const float* __restrict__ n2w, const float* __restrict__ n2b,
    const float* __restrict__ n2g, const float* __restrict__ n2beta,
    const float* __restrict__ n2m, const float* __restrict__ n2v,
    const unsigned short* __restrict__ OWc,
    const float* __restrict__ ob, const float* __restrict__ og,
    const float* __restrict__ obeta, const float* __restrict__ om,
    const float* __restrict__ ov,
    float* __restrict__ out1)
{
  __shared__ Smem3 sm;
  int xcd = blockIdx.x & 7, idx = blockIdx.x >> 3;
  int b = xcd*2 + (idx >> 4), pt64 = idx & 15;
  int p0 = pt64 * 64;
  int t = threadIdx.x, w = t >> 6, lane = t & 63;
  int l15 = lane & 15, sg = lane >> 4;

  // staging roles: wave -> (s-octet so, c-half ch); lane -> (q4, c3, jh)
  int so = w & 3, ch = w >> 2;
  int q4 = lane & 3, c3 = (lane >> 2) & 7, jh = (lane >> 5) & 1;
  int c_l = ch*8 + c3, s0 = so*8 + jh*4;
  // per-cblk F base for this thread (advance by cblk*16 c-rows)
  const float* fsrc0 = &F[((size_t)((b*64 + c_l)*32) + s0)*NPP + p0 + q4*4];

  // ---- issue cblk0 F loads (hidden under phase 0) ----
  float4 fv[4][4];   // [jj][qg]
  #pragma unroll
  for (int jj = 0; jj < 4; ++jj)
    #pragma unroll
    for (int qg = 0; qg < 4; ++qg)
      fv[jj][qg] = *(const float4*)&fsrc0[(size_t)jj*NPP + qg*16];

  // ---- phase 0a: gx, density, d2 for all 64 points ----
  int pp8 = t >> 3, si8 = t & 7;
  const float* g = &GX[(size_t)(b*NPP + p0 + pp8)*96 + si8*12];
  float4 f0 = *(const float4*)g;
  float4 f1 = *(const float4*)(g + 4);
  float4 f2 = *(const float4*)(g + 8);

  if (t < 32) {
    float sc = whg[t] * rsqrtf(whv[t] + 1e-5f);
    sm.cst[t]    = whw[t*3+0] * sc;
    sm.cst[32+t] = whw[t*3+1] * sc;
    sm.cst[64+t] = whw[t*3+2] * sc;
    sm.cst[96+t] = (whb[t] - whm[t]) * sc + whbeta[t];
  } else if (t < 48) {
    int i = t - 32;
    float sc = n1g[i] * rsqrtf(n1v[i] + 1e-5f);
    sm.cst[128+i] = n1w[i] * sc;
    sm.cst[144+i] = (n1b[i] - n1m[i]) * sc + n1beta[i];
  } else if (t < 64) {
    int i = t - 48;
    float sc = n2g[0] * rsqrtf(n2v[0] + 1e-5f);
    sm.cst[160+i] = n2w[i] * sc;
    if (i == 0) sm.cst[176] = (n2b[0] - n2m[0]) * sc + n2beta[0];
  }
  __syncthreads();

  {
    float xs[4], ys[4], zs[4], inv[4];
    xs[0]=f0.x; ys[0]=f0.y; zs[0]=f0.z;
    xs[1]=f0.w; ys[1]=f1.x; zs[1]=f1.y;
    xs[2]=f1.z; ys[2]=f1.w; zs[2]=f2.x;
    xs[3]=f2.y; ys[3]=f2.z; zs[3]=f2.w;
    if (si8 == 0) { xs[0]=0.f; ys[0]=0.f; zs[0]=0.f; }   // s=0 zeroed per reference
    float mx = 0.f;
    #pragma unroll
    for (int u = 0; u < 4; ++u) {
      float den = xs[u] + ys[u] + zs[u];
      if (den < 1e-10f) den = 1e-10f;
      inv[u] = 1.0f / den;
      mx = fmaxf(mx, inv[u]);
    }
    #pragma unroll
    for (int m = 1; m < 8; m <<= 1) mx = fmaxf(mx, __shfl_xor(mx, m, 8));
    #pragma unroll
    for (int u = 0; u < 4; ++u) {
      float ds = inv[u] / mx;
      float acc = sm.cst[176];
      #pragma unroll
      for (int i = 0; i < 16; ++i) {
        float d1 = fmaxf(ds * sm.cst[128+i] + sm.cst[144+i], 0.f);
        acc += d1 * sm.cst[160+i];
      }
      float d2 = 1.0f / (1.0f + expf(-acc));
      float4 st = {xs[u], ys[u], zs[u], d2};
      *(float4*)&sm.u.ph0.gxd[(size_t)(pp8*32 + si8*4 + u)*4] = st;
    }
  }
  __syncthreads();

  // ---- phase 0b: wd (intra-wave) + bfr hoist, per pg ----
  const f32x4 z4 = {0,0,0,0};
  int phKh = (lane >> 4) & 1;
  int phPp = w*2 + (lane >> 5);
  int phSi = lane & 15;
  int ppA = w*2, ppB = w*2 + 1;
  int c0 = l15*32 + sg*8;

  short8 bfrA[4][2], bfrB[4][2];       // [pg][kh]
  #pragma unroll
  for (int pg = 0; pg < 4; ++pg) {
    const float4 ga = *(const float4*)&sm.u.ph0.gxd[(size_t)((pg*16 + phPp)*32 + phSi*2)*4];
    const float4 gb = *(const float4*)&sm.u.ph0.gxd[(size_t)((pg*16 + phPp)*32 + phSi*2 + 1)*4];
    #pragma unroll
    for (int ki = 0; ki < 16; ++ki) {
      int k = phKh*16 + ki;
      float a0 = sm.cst[k], a1 = sm.cst[32+k], a2 = sm.cst[64+k], bc = sm.cst[96+k];
      float w0 = fmaxf(ga.x*a0 + ga.y*a1 + ga.z*a2 + bc, 0.f) * ga.w;
      float w1 = fmaxf(gb.x*a0 + gb.y*a1 + gb.z*a2 + bc, 0.f) * gb.w;
      unsigned r = (unsigned)f2bf(w0) | ((unsigned)f2bf(w1) << 16);
      *(unsigned*)&sm.u.ph0.wd[(phPp*32 + k)*32 + phSi*2] = r;
    }
    #pragma unroll
    for (int kh = 0; kh < 2; ++kh) {   // intra-wave RAW on wd
      bfrA[pg][kh] = *(const short8*)&sm.u.ph0.wd[(ppA*32 + kh*16 + l15)*32 + sg*8];
      bfrB[pg][kh] = *(const short8*)&sm.u.ph0.wd[(ppB*32 + kh*16 + l15)*32 + sg*8];
    }
  }
  __syncthreads();   // gxd+wd dead; fs may overwrite

  // ---- main loop: per cblk: {fs write; bar; af+stage1 (+issue next F); bar; stage2; bar} ----
  int w4 = w & 3, gp0 = (w >> 2) * 2;
  f32x4 acc00 = {0,0,0,0}, acc10 = {0,0,0,0}, acc01 = {0,0,0,0}, acc11 = {0,0,0,0};
  int rowG0 = gp0*16 + l15, rowG1 = (gp0+1)*16 + l15;
  unsigned sw0 = (rowG0 & 15) << 4, sw1 = (rowG1 & 15) << 4;
  const char* bbase0 = sm.mm + rowG0*1024;
  const char* bbase1 = sm.mm + rowG1*1024;
  int fsbase = so*128 + c_l*8 + jh*4;  // u16 idx, + p*512 + jp*2

  #pragma unroll
  for (int cblk = 0; cblk < 4; ++cblk) {
    // cvt + pack pairs + swizzled LDS scatter (4-way bank max)
    #pragma unroll
    for (int qg = 0; qg < 4; ++qg)
      #pragma unroll
      for (int pi = 0; pi < 4; ++pi) {
        int p = qg*16 + q4*4 + pi;
        unsigned sw = (unsigned)(p & 15) << 3;
        #pragma unroll
        for (int jp = 0; jp < 2; ++jp) {
          unsigned u = (unsigned)f2bf(((const float*)&fv[jp*2][qg])[pi])
                     | ((unsigned)f2bf(((const float*)&fv[jp*2+1][qg])[pi]) << 16);
          unsigned fidx = (unsigned)(p*512 + fsbase + jp*2) ^ sw;
          *(unsigned*)&sm.u.fs[fidx] = u;
        }
      }
    __syncthreads();

    // af loads (1KB-dense b128 with matching XOR)
    short8 afA[4], afB[4];
    unsigned swA = (unsigned)(ppA & 15) << 3, swB = (unsigned)(ppB & 15) << 3;
    #pragma unroll
    for (int pg = 0; pg < 4; ++pg) {
      unsigned iA = (unsigned)((pg*16 + ppA)*512 + sg*128 + l15*8) ^ swA;
      unsigned iB = (unsigned)((pg*16 + ppB)*512 + sg*128 + l15*8) ^ swB;
      afA[pg] = *(const short8*)&sm.u.fs[iA];
      afB[pg] = *(const short8*)&sm.u.fs[iB];
    }
    // issue next cblk's F loads (hidden under stage1/stage2)
    if (cblk < 3) {
      const float* fsrc = fsrc0 + (size_t)(cblk + 1) * 16 * 32 * NPP;
      #pragma unroll
      for (int jj = 0; jj < 4; ++jj)
        #pragma unroll
        for (int qg = 0; qg < 4; ++qg)
          fv[jj][qg] = *(const float4*)&fsrc[(size_t)jj*NPP + qg*16];
    }
    // stage 1: MFMA -> mm (XOR-swizzled rows)
    #pragma unroll
    for (int pg = 0; pg < 4; ++pg) {
      f32x4 mA0 = __builtin_amdgcn_mfma_f32_16x16x32_bf16(afA[pg], bfrA[pg][0], z4, 0,0,0);
      f32x4 mA1 = __builtin_amdgcn_mfma_f32_16x16x32_bf16(afA[pg], bfrA[pg][1], z4, 0,0,0);
      f32x4 mB0 = __builtin_amdgcn_mfma_f32_16x16x32_bf16(afB[pg], bfrB[pg][0], z4, 0,0,0);
      f32x4 mB1 = __builtin_amdgcn_mfma_f32_16x16x32_bf16(afB[pg], bfrB[pg][1], z4, 0,0,0);
      int rowA = pg*16 + ppA, rowB = pg*16 + ppB;
      unsigned swa = (rowA & 15) << 4, swb = (rowB & 15) << 4;
      char* bA = sm.mm + rowA*1024;
      char* bB = sm.mm + rowB*1024;
      *(unsigned long long*)(bA + ((c0      ) ^ swa)) = pack4bf(mA0);
      *(unsigned long long*)(bA + ((c0 + 512) ^ swa)) = pack4bf(mA1);
      *(unsigned long long*)(bB + ((c0      ) ^ swb)) = pack4bf(mB0);
      *(unsigned long long*)(bB + ((c0 + 512) ^ swb)) = pack4bf(mB1);
    }
    __syncthreads();
    // stage 2: OWc x mm, accumulate
    {
      const unsigned short* ac = &OWc[(size_t)((w4*4 + cblk)*16)*1024 + lane*8];
      #pragma unroll 8
      for (int tt = 0; tt < 16; ++tt) {
        short8 a0 = *(const short8*)&ac[tt*1024];
        short8 a1 = *(const short8*)&ac[tt*1024 + 512];
        int col = sg*16 + tt*64;
        short8 b0 = *(const short8*)(bbase0 + (col ^ sw0));
        short8 b1 = *(const short8*)(bbase1 + (col ^ sw1));
        acc00 = __builtin_amdgcn_mfma_f32_16x16x32_bf16(a0, b0, acc00, 0,0,0);
        acc10 = __builtin_amdgcn_mfma_f32_16x16x32_bf16(a1, b0, acc10, 0,0,0);
        acc01 = __builtin_amdgcn_mfma_f32_16x16x32_bf16(a0, b1, acc01, 0,0,0);
        acc11 = __builtin_amdgcn_mfma_f32_16x16x32_bf16(a1, b1, acc11, 0,0,0);
      }
    }
    __syncthreads();
  }

  // ---- epilogue: +bias, BN, f32 store ----
  #pragma unroll
  for (int hi = 0; hi < 2; ++hi)
    #pragma unroll
    for (int gg = 0; gg < 2; ++gg) {
      f32x4 a = hi ? (gg ? acc11 : acc10) : (gg ? acc01 : acc00);
      #pragma unroll
      for (int r = 0; r < 4; ++r) {
        int o = w4*32 + hi*16 + sg*4 + r;
        float sc = og[o] * rsqrtf(ov[o] + 1e-5f);
        float dd = (ob[o] - om[o]) * sc + obeta[o];
        out1[(size_t)(b*128 + o)*NPP + p0 + (gp0+gg)*16 + l15] = a[r] * sc + dd;
      }
    }
}

extern "C" void kernel_launch(void* const* d_in, const int* in_sizes, int n_in,
                              void* d_out, int out_size, void* d_ws, size_t ws_size,
                              hipStream_t stream) {
  (void)in_sizes; (void)n_in; (void)out_size; (void)ws_size;
  const float* new_xyz = (const float*)d_in[0];
  const float* gxyz    = (const float*)d_in[1];
  const float* gfeat   = (const float*)d_in[2];
  const float* whw     = (const float*)d_in[3];
  const float* whb     = (const float*)d_in[4];
  const float* whg     = (const float*)d_in[5];
  const float* whbeta  = (const float*)d_in[6];
  const float* whm     = (const float*)d_in[7];
  const float* whv     = (const float*)d_in[8];
  const float* n1w     = (const float*)d_in[9];
  const float* n1b     = (const float*)d_in[10];
  const float* n1g     = (const float*)d_in[11];
  const float* n1beta  = (const float*)d_in[12];
  const float* n1m     = (const float*)d_in[13];
  const float* n1v     = (const float*)d_in[14];
  const float* n2w     = (const float*)d_in[15];
  const float* n2b     = (const float*)d_in[16];
  const float* n2g     = (const float*)d_in[17];
  const float* n2beta  = (const float*)d_in[18];
  const float* n2m     = (const float*)d_in[19];
  const float* n2v     = (const float*)d_in[20];
  const float* out_w   = (const float*)d_in[21];
  const float* out_b   = (const float*)d_in[22];
  const float* out_g   = (const float*)d_in[23];
  const float* out_bt  = (const float*)d_in[24];
  const float* out_m   = (const float*)d_in[25];
  const float* out_v   = (const float*)d_in[26];

  unsigned short* owc = (unsigned short*)d_ws;   // 512 KB chunk-major weights
  float* out0 = (float*)d_out;                   // [16][1024][3] f32
  float* out1 = out0 + 16*1024*3;                // [16][128][1024] f32

  hipLaunchKernelGGL(k_prep, dim3(320), dim3(256), 0, stream, out_w, new_xyz, owc, out0);
  hipLaunchKernelGGL(k_main, dim3(256), dim3(512), 0, stream,
      gfeat, gxyz, whw, whb, whg, whbeta, whm, whv,
      n1w, n1b, n1g, n1beta, n1m, n1v,
      n2w, n2b, n2g, n2beta, n2m, n2v,
      owc, out_b, out_g, out_bt, out_m, out_v, out1);
}